// Round 27
// baseline (65.171 us; speedup 1.0000x reference)
//
#include <hip/hip_runtime.h>
#include <hip/hip_bf16.h>

#define NROWS 16384   // B*S
#define KD    2048    // D
#define NE    16      // experts
#define ROWS_PER_BLK 32
#define KQ    512     // K per staged phase
#define NPH   4       // phases
#define TPP   8       // 64-float tiles per phase (4 per kg-wave)

// v24: 2 blocks/CU for 4 waves/SIMD with independent barrier domains.
//  - block = 512 thr / 8 waves / 32 rows; grid 512 = 2 blocks/CU
//  - wave w -> (expert-quartet eq=w&3, K-half kg=w>>2); R=4 rows/lane
//  - acc = 4 rows x 4 e x 2 m = 32 floats (proven no-spill); 16:1 FMA:ds_read
//  - W quarter [32][512] = 64 KB staged per phase (4 phases, 8 gload/thread);
//    kg0 computes tiles 0-3 of each phase, kg1 tiles 4-7 (K partition, summed)
//  - epilogue: seg-butterfly -> slab[2][32][33] -> kg-combine -> row epilogue
// Output FLOAT32: [262144 probs][32768 ids-as-floats].

__device__ __forceinline__ void gload_lds16(const float* g, float* l) {
    __builtin_amdgcn_global_load_lds(
        (const __attribute__((address_space(1))) void*)g,
        (__attribute__((address_space(3))) void*)l,
        16, 0, 0);
}

__global__ __launch_bounds__(512)
void noisy_router_kernel(const float* __restrict__ x,
                         const float* __restrict__ noise,
                         const float* __restrict__ Wfc,
                         const float* __restrict__ bfc,
                         const float* __restrict__ Wns,
                         const float* __restrict__ bns,
                         float* __restrict__ out)
{
    // [0,16384): W quarter [32 rows][512]; [16384,18496): slab [2][32][33]
    __shared__ float lds[32 * KQ + 2 * 32 * 33];   // 73,984 B -> 2 blocks/CU

    const int tid  = threadIdx.x;
    const int lane = tid & 63;
    const int w    = tid >> 6;     // 0..7
    const int eq   = w & 3;        // expert quartet 0..3
    const int kg   = w >> 2;       // K-half 0..1
    const int seg  = lane & 7;
    const int rgrp = lane >> 3;

    const int rowbase = blockIdx.x * ROWS_PER_BLK + rgrp * 4;   // 4 rows/lane

    // staging map: instr i (0..7) covers W-stack rows 4i..4i+3 of the phase's
    // [32][512] tile: thread -> row 4i+(tid>>7), col (tid&127)*4;
    // dest byte = i*8192 + tid*16 (uniform base + lane*16: legal form).
    const int swr  = tid >> 7;             // 0..3
    const int scol = (tid & 127) * 4;

    const float* xb = x + (size_t)rowbase * KD + seg * 8;

    float accA[4][4], accB[4][4];          // 32 floats (proven no-spill size)
    #pragma unroll
    for (int j = 0; j < 4; ++j)
        #pragma unroll
        for (int e = 0; e < 4; ++e) { accA[j][e] = 0.f; accB[j][e] = 0.f; }

    #pragma unroll 1
    for (int p = 0; p < NPH; ++p) {
        const int kbase = p * KQ;
        __syncthreads();                       // all reads of prev phase done
        {
            #pragma unroll
            for (int i = 0; i < 8; ++i) {
                const int wr = 4 * i + swr;    // W-stack row 0..31
                const float* gsrc = (wr < 16 ? Wfc + (size_t)wr * KD
                                             : Wns + (size_t)(wr - 16) * KD)
                                    + kbase + scol;
                gload_lds16(gsrc, lds + i * 2048 + tid * 4);
            }
        }
        __syncthreads();                       // phase staged (vmcnt drained)

        const float* wp0 = lds + (eq * 4) * KQ + seg * 8;        // Wfc rows
        const float* wp1 = lds + (16 + eq * 4) * KQ + seg * 8;   // Wns rows
        const float* xh  = xb + kbase;

        // ---- this wave's 4 tiles of the phase (kg partitions K), no barriers ----
        #pragma unroll 2
        for (int c = 0; c < 4; ++c) {
            const int t = kg * 4 + c;          // tile 0..7 within phase
            float4 xv[4][2];
            #pragma unroll
            for (int j = 0; j < 4; ++j) {
                xv[j][0] = *(const float4*)(xh + (size_t)j * KD + t * 64);
                xv[j][1] = *(const float4*)(xh + (size_t)j * KD + t * 64 + 4);
            }
            #pragma unroll
            for (int e = 0; e < 4; ++e) {
                const float4 a0 = *(const float4*)(wp0 + e * KQ + t * 64);
                const float4 a1 = *(const float4*)(wp0 + e * KQ + t * 64 + 4);
                const float4 b0 = *(const float4*)(wp1 + e * KQ + t * 64);
                const float4 b1 = *(const float4*)(wp1 + e * KQ + t * 64 + 4);
                #pragma unroll
                for (int j = 0; j < 4; ++j) {
                    const float4 x0 = xv[j][0], x1 = xv[j][1];
                    float sA = accA[j][e], sB = accB[j][e];
                    sA = fmaf(x0.x, a0.x, sA); sA = fmaf(x0.y, a0.y, sA);
                    sA = fmaf(x0.z, a0.z, sA); sA = fmaf(x0.w, a0.w, sA);
                    sA = fmaf(x1.x, a1.x, sA); sA = fmaf(x1.y, a1.y, sA);
                    sA = fmaf(x1.z, a1.z, sA); sA = fmaf(x1.w, a1.w, sA);
                    sB = fmaf(x0.x, b0.x, sB); sB = fmaf(x0.y, b0.y, sB);
                    sB = fmaf(x0.z, b0.z, sB); sB = fmaf(x0.w, b0.w, sB);
                    sB = fmaf(x1.x, b1.x, sB); sB = fmaf(x1.y, b1.y, sB);
                    sB = fmaf(x1.z, b1.z, sB); sB = fmaf(x1.w, b1.w, sB);
                    accA[j][e] = sA; accB[j][e] = sB;
                }
            }
        }
    }

    // ---- butterfly over the 8 k-segs (masks 1,2,4 stay within seg-group) ----
    #pragma unroll
    for (int j = 0; j < 4; ++j)
        #pragma unroll
        for (int e = 0; e < 4; ++e) {
            float a = accA[j][e], b = accB[j][e];
            a += __shfl_xor(a, 1); a += __shfl_xor(a, 2); a += __shfl_xor(a, 4);
            b += __shfl_xor(b, 1); b += __shfl_xor(b, 2); b += __shfl_xor(b, 4);
            accA[j][e] = a; accB[j][e] = b;
        }

    __syncthreads();                  // all W reads done
    float* const slab = lds + 32 * KQ;   // [2 kg][32 rows][stride 33]

    if (seg == 0) {                   // writer per (kg, row, e-quartet)
        #pragma unroll
        for (int j = 0; j < 4; ++j) {
            float* dst = slab + kg * 1056 + (rgrp * 4 + j) * 33 + eq * 4;
            #pragma unroll
            for (int e = 0; e < 4; ++e) { dst[e] = accA[j][e]; dst[16 + e] = accB[j][e]; }
        }
    }
    __syncthreads();

    {   // combine kg partials in place (1024 elems / 512 thr = 2 each)
        const int idx = tid * 2;
        const int r   = idx >> 5;          // 0..31
        const int o   = idx & 31;          // even
        slab[r * 33 + o]     += slab[1056 + r * 33 + o];
        slab[r * 33 + o + 1] += slab[1056 + r * 33 + o + 1];
    }
    __syncthreads();

    // ---- per-row epilogue: softplus noise, top-2, sparse softmax ----
    if (tid < ROWS_PER_BLK) {
        const int r = tid;
        const float* rowp = slab + r * 33;
        const size_t grow = (size_t)blockIdx.x * ROWS_PER_BLK + r;
        const float* nzp = noise + grow * NE;

        float m1 = -1e30f, m2 = -1e30f;
        int i1 = 0, i2 = 0;
        #pragma unroll
        for (int j = 0; j < NE; ++j) {
            const float z  = rowp[16 + j] + bns[j];
            const float sp = fmaxf(z, 0.f) + log1pf(expf(-fabsf(z)));  // jax softplus
            const float v  = fmaf(nzp[j], sp, rowp[j] + bfc[j]);
            if (v > m1)      { m2 = m1; i2 = i1; m1 = v; i1 = j; }     // ties -> lower idx
            else if (v > m2) { m2 = v;  i2 = j; }
        }
        const float e2  = expf(m2 - m1);
        const float inv = 1.f / (1.f + e2);

        float* po = out + grow * NE;
        #pragma unroll
        for (int j = 0; j < NE; ++j) {
            po[j] = (j == i1) ? inv : ((j == i2) ? e2 * inv : 0.f);
        }
        float* pi = out + (size_t)NROWS * NE + grow * 2;
        pi[0] = (float)i1;
        pi[1] = (float)i2;
    }
}

extern "C" void kernel_launch(void* const* d_in, const int* in_sizes, int n_in,
                              void* d_out, int out_size, void* d_ws, size_t ws_size,
                              hipStream_t stream)
{
    const float* x     = (const float*)d_in[0];
    const float* noise = (const float*)d_in[1];
    const float* Wfc   = (const float*)d_in[2];
    const float* bfc   = (const float*)d_in[3];
    const float* Wns   = (const float*)d_in[4];
    const float* bns   = (const float*)d_in[5];
    float* out = (float*)d_out;

    noisy_router_kernel<<<NROWS / ROWS_PER_BLK, 512, 0, stream>>>(
        x, noise, Wfc, bfc, Wns, bns, out);
}

// Round 28
// 51.428 us; speedup vs baseline: 1.2672x; 1.2672x over previous
//
#include <hip/hip_runtime.h>
#include <hip/hip_bf16.h>

#define NROWS 16384   // B*S
#define KD    2048    // D
#define NE    16      // experts
#define ROWS_PER_BLK 64
#define KH    1024    // K-half resident in LDS
#define TPH   16      // tiles of 64 K-floats per half

// v25 = v21 (barrier-free champion, 48.7us) + raw s_barrier every 2 tiles.
// Mechanism under test: inter-wave drift. 8 waves read the same 16KB x window
// per tile with no sync for 16 tiles; drifted waves lose the 4x-dup L1 hits
// (L1 32KB ~ 2-tile window) and pay L2/HBM latency. Raw s_barrier (NOT
// __syncthreads -- no data deps in loop, no waitcnt drain needed) rate-limits
// drift only.
//  - block = 512 thr / 8 waves / 64 rows; grid 256 = 1 block/CU
//  - wave w -> (expert-quartet eq=w&3, row-half rh=w>>2); x-dup 4x
//  - lane = (rgrp=lane>>3 -> 4 rows, seg=lane&7); acc = 32 floats (no-spill)
//  - W K-half [32][1024] = 128 KB resident in LDS; staged twice
// Output FLOAT32: [262144 probs][32768 ids-as-floats].

__device__ __forceinline__ void gload_lds16(const float* g, float* l) {
    __builtin_amdgcn_global_load_lds(
        (const __attribute__((address_space(1))) void*)g,
        (__attribute__((address_space(3))) void*)l,
        16, 0, 0);
}

__global__ __launch_bounds__(512)
void noisy_router_kernel(const float* __restrict__ x,
                         const float* __restrict__ noise,
                         const float* __restrict__ Wfc,
                         const float* __restrict__ bfc,
                         const float* __restrict__ Wns,
                         const float* __restrict__ bns,
                         float* __restrict__ out)
{
    // [0, 32768): W-half [32 rows][1024];  [32768, 34880): epilogue slab [64][33]
    __shared__ float lds[32 * KH + ROWS_PER_BLK * 33];   // 139.5 KB

    const int tid  = threadIdx.x;
    const int lane = tid & 63;
    const int w    = tid >> 6;     // 0..7
    const int eq   = w & 3;        // expert quartet 0..3
    const int rh   = w >> 2;       // row half 0..1
    const int seg  = lane & 7;
    const int rgrp = lane >> 3;

    const int rowbase = blockIdx.x * ROWS_PER_BLK + rh * 32 + rgrp * 4;

    // staging map: instr i (0..15) writes W-stack rows {2i, 2i+1}:
    // thread tid -> row 2i + (tid>>8), col (tid&255)*4; dest = i*8KB + tid*16B
    // (uniform base + lane*16: legal form). Rows 0..15 = Wfc, 16..31 = Wns.
    const int wrb  = tid >> 8;             // 0 or 1
    const int scol = (tid & 255) * 4;

    const float* xb = x + (size_t)rowbase * KD + seg * 8;

    float accA[4][4], accB[4][4];          // 32 floats (proven no-spill size)
    #pragma unroll
    for (int j = 0; j < 4; ++j)
        #pragma unroll
        for (int e = 0; e < 4; ++e) { accA[j][e] = 0.f; accB[j][e] = 0.f; }

    #pragma unroll 1
    for (int h = 0; h < 2; ++h) {
        const int kbase = h * KH;
        __syncthreads();                       // phase boundary: all reads of prev half done
        {
            const float* srcF = Wfc + (size_t)wrb * KD + kbase + scol;   // i = 0..7
            const float* srcN = Wns + (size_t)wrb * KD + kbase + scol;   // i = 8..15
            #pragma unroll
            for (int i = 0; i < 8; ++i)
                gload_lds16(srcF + (size_t)(2 * i) * KD, lds + i * 2048 + tid * 4);
            #pragma unroll
            for (int i = 0; i < 8; ++i)
                gload_lds16(srcN + (size_t)(2 * i) * KD, lds + (8 + i) * 2048 + tid * 4);
        }
        __syncthreads();                       // W-half staged (vmcnt drained)

        const float* wp0 = lds + (eq * 4) * KH + seg * 8;        // Wfc rows
        const float* wp1 = lds + (16 + eq * 4) * KH + seg * 8;   // Wns rows
        const float* xh  = xb + kbase;

        // ---- 16 tiles; raw s_barrier each pair keeps waves in L1 window ----
        #pragma unroll 2
        for (int t = 0; t < TPH; ++t) {
            if ((t & 1) == 0) __builtin_amdgcn_s_barrier();   // lockstep, no drain
            float4 xv[4][2];
            #pragma unroll
            for (int j = 0; j < 4; ++j) {
                xv[j][0] = *(const float4*)(xh + (size_t)j * KD + t * 64);
                xv[j][1] = *(const float4*)(xh + (size_t)j * KD + t * 64 + 4);
            }
            #pragma unroll
            for (int e = 0; e < 4; ++e) {
                const float4 a0 = *(const float4*)(wp0 + e * KH + t * 64);
                const float4 a1 = *(const float4*)(wp0 + e * KH + t * 64 + 4);
                const float4 b0 = *(const float4*)(wp1 + e * KH + t * 64);
                const float4 b1 = *(const float4*)(wp1 + e * KH + t * 64 + 4);
                #pragma unroll
                for (int j = 0; j < 4; ++j) {
                    const float4 x0 = xv[j][0], x1 = xv[j][1];
                    float sA = accA[j][e], sB = accB[j][e];
                    sA = fmaf(x0.x, a0.x, sA); sA = fmaf(x0.y, a0.y, sA);
                    sA = fmaf(x0.z, a0.z, sA); sA = fmaf(x0.w, a0.w, sA);
                    sA = fmaf(x1.x, a1.x, sA); sA = fmaf(x1.y, a1.y, sA);
                    sA = fmaf(x1.z, a1.z, sA); sA = fmaf(x1.w, a1.w, sA);
                    sB = fmaf(x0.x, b0.x, sB); sB = fmaf(x0.y, b0.y, sB);
                    sB = fmaf(x0.z, b0.z, sB); sB = fmaf(x0.w, b0.w, sB);
                    sB = fmaf(x1.x, b1.x, sB); sB = fmaf(x1.y, b1.y, sB);
                    sB = fmaf(x1.z, b1.z, sB); sB = fmaf(x1.w, b1.w, sB);
                    accA[j][e] = sA; accB[j][e] = sB;
                }
            }
        }
    }

    // ---- butterfly over the 8 k-segs (masks 1,2,4 stay within seg-group) ----
    #pragma unroll
    for (int j = 0; j < 4; ++j)
        #pragma unroll
        for (int e = 0; e < 4; ++e) {
            float a = accA[j][e], b = accB[j][e];
            a += __shfl_xor(a, 1); a += __shfl_xor(a, 2); a += __shfl_xor(a, 4);
            b += __shfl_xor(b, 1); b += __shfl_xor(b, 2); b += __shfl_xor(b, 4);
            accA[j][e] = a; accB[j][e] = b;
        }

    __syncthreads();                  // all W reads done; slab region free anyway
    float* const slab = lds + 32 * KH;   // [64 rows][stride 33]

    if (seg == 0) {                   // each wave owns complete (row, e-quartet) outs
        #pragma unroll
        for (int j = 0; j < 4; ++j) {
            float* dst = slab + (rh * 32 + rgrp * 4 + j) * 33 + eq * 4;
            #pragma unroll
            for (int e = 0; e < 4; ++e) { dst[e] = accA[j][e]; dst[16 + e] = accB[j][e]; }
        }
    }
    __syncthreads();

    // ---- per-row epilogue: softplus noise, top-2, sparse softmax ----
    if (tid < ROWS_PER_BLK) {
        const int r = tid;
        const float* rowp = slab + r * 33;
        const size_t grow = (size_t)blockIdx.x * ROWS_PER_BLK + r;
        const float* nzp = noise + grow * NE;

        float m1 = -1e30f, m2 = -1e30f;
        int i1 = 0, i2 = 0;
        #pragma unroll
        for (int j = 0; j < NE; ++j) {
            const float z  = rowp[16 + j] + bns[j];
            const float sp = fmaxf(z, 0.f) + log1pf(expf(-fabsf(z)));  // jax softplus
            const float v  = fmaf(nzp[j], sp, rowp[j] + bfc[j]);
            if (v > m1)      { m2 = m1; i2 = i1; m1 = v; i1 = j; }     // ties -> lower idx
            else if (v > m2) { m2 = v;  i2 = j; }
        }
        const float e2  = expf(m2 - m1);
        const float inv = 1.f / (1.f + e2);

        float* po = out + grow * NE;
        #pragma unroll
        for (int j = 0; j < NE; ++j) {
            po[j] = (j == i1) ? inv : ((j == i2) ? e2 * inv : 0.f);
        }
        float* pi = out + (size_t)NROWS * NE + grow * 2;
        pi[0] = (float)i1;
        pi[1] = (float)i2;
    }
}

extern "C" void kernel_launch(void* const* d_in, const int* in_sizes, int n_in,
                              void* d_out, int out_size, void* d_ws, size_t ws_size,
                              hipStream_t stream)
{
    const float* x     = (const float*)d_in[0];
    const float* noise = (const float*)d_in[1];
    const float* Wfc   = (const float*)d_in[2];
    const float* bfc   = (const float*)d_in[3];
    const float* Wns   = (const float*)d_in[4];
    const float* bns   = (const float*)d_in[5];
    float* out = (float*)d_out;

    noisy_router_kernel<<<NROWS / ROWS_PER_BLK, 512, 0, stream>>>(
        x, noise, Wfc, bfc, Wns, bns, out);
}

// Round 29
// 48.626 us; speedup vs baseline: 1.3402x; 1.0576x over previous
//
#include <hip/hip_runtime.h>
#include <hip/hip_bf16.h>

#define NROWS 16384   // B*S
#define KD    2048    // D
#define NE    16      // experts
#define ROWS_PER_BLK 64
#define KH    1024    // K-half resident in LDS
#define TPH   16      // tiles of 64 K-floats per half

// v26 = v21 (barrier-free champion, 48.7us) with inner-loop unroll 2 -> 4.
// VGPR 88 leaves ~40-reg headroom; unroll-4 lets the scheduler keep 3-4 tiles
// of x loads in flight (~1500cy lookahead) to cover L2-miss/L3 latency, which
// the per-tile accounting (3.65k cy vs 1.5k pipe floor) says is the residual.
//  - block = 512 thr / 8 waves / 64 rows; grid 256 = 1 block/CU
//  - wave w -> (expert-quartet eq=w&3, row-half rh=w>>2); x-dup 4x
//  - lane = (rgrp=lane>>3 -> 4 rows, seg=lane&7); acc = 32 floats (no-spill)
//  - W K-half [32][1024] = 128 KB resident in LDS; staged twice; 3 barriers
// Output FLOAT32: [262144 probs][32768 ids-as-floats].

__device__ __forceinline__ void gload_lds16(const float* g, float* l) {
    __builtin_amdgcn_global_load_lds(
        (const __attribute__((address_space(1))) void*)g,
        (__attribute__((address_space(3))) void*)l,
        16, 0, 0);
}

__global__ __launch_bounds__(512)
void noisy_router_kernel(const float* __restrict__ x,
                         const float* __restrict__ noise,
                         const float* __restrict__ Wfc,
                         const float* __restrict__ bfc,
                         const float* __restrict__ Wns,
                         const float* __restrict__ bns,
                         float* __restrict__ out)
{
    // [0, 32768): W-half [32 rows][1024];  [32768, 34880): epilogue slab [64][33]
    __shared__ float lds[32 * KH + ROWS_PER_BLK * 33];   // 139.5 KB

    const int tid  = threadIdx.x;
    const int lane = tid & 63;
    const int w    = tid >> 6;     // 0..7
    const int eq   = w & 3;        // expert quartet 0..3
    const int rh   = w >> 2;       // row half 0..1
    const int seg  = lane & 7;
    const int rgrp = lane >> 3;

    const int rowbase = blockIdx.x * ROWS_PER_BLK + rh * 32 + rgrp * 4;

    // staging map: instr i (0..15) writes W-stack rows {2i, 2i+1}:
    // thread tid -> row 2i + (tid>>8), col (tid&255)*4; dest = i*8KB + tid*16B
    // (uniform base + lane*16: legal form). Rows 0..15 = Wfc, 16..31 = Wns.
    const int wrb  = tid >> 8;             // 0 or 1
    const int scol = (tid & 255) * 4;

    const float* xb = x + (size_t)rowbase * KD + seg * 8;

    float accA[4][4], accB[4][4];          // 32 floats (proven no-spill size)
    #pragma unroll
    for (int j = 0; j < 4; ++j)
        #pragma unroll
        for (int e = 0; e < 4; ++e) { accA[j][e] = 0.f; accB[j][e] = 0.f; }

    #pragma unroll 1
    for (int h = 0; h < 2; ++h) {
        const int kbase = h * KH;
        __syncthreads();                       // phase boundary: all reads of prev half done
        {
            const float* srcF = Wfc + (size_t)wrb * KD + kbase + scol;   // i = 0..7
            const float* srcN = Wns + (size_t)wrb * KD + kbase + scol;   // i = 8..15
            #pragma unroll
            for (int i = 0; i < 8; ++i)
                gload_lds16(srcF + (size_t)(2 * i) * KD, lds + i * 2048 + tid * 4);
            #pragma unroll
            for (int i = 0; i < 8; ++i)
                gload_lds16(srcN + (size_t)(2 * i) * KD, lds + (8 + i) * 2048 + tid * 4);
        }
        __syncthreads();                       // W-half staged (vmcnt drained)

        const float* wp0 = lds + (eq * 4) * KH + seg * 8;        // Wfc rows
        const float* wp1 = lds + (16 + eq * 4) * KH + seg * 8;   // Wns rows
        const float* xh  = xb + kbase;

        // ---- 16 tiles, ZERO barriers; unroll 4 for deep load pipelining ----
        #pragma unroll 4
        for (int t = 0; t < TPH; ++t) {
            float4 xv[4][2];
            #pragma unroll
            for (int j = 0; j < 4; ++j) {
                xv[j][0] = *(const float4*)(xh + (size_t)j * KD + t * 64);
                xv[j][1] = *(const float4*)(xh + (size_t)j * KD + t * 64 + 4);
            }
            #pragma unroll
            for (int e = 0; e < 4; ++e) {
                const float4 a0 = *(const float4*)(wp0 + e * KH + t * 64);
                const float4 a1 = *(const float4*)(wp0 + e * KH + t * 64 + 4);
                const float4 b0 = *(const float4*)(wp1 + e * KH + t * 64);
                const float4 b1 = *(const float4*)(wp1 + e * KH + t * 64 + 4);
                #pragma unroll
                for (int j = 0; j < 4; ++j) {
                    const float4 x0 = xv[j][0], x1 = xv[j][1];
                    float sA = accA[j][e], sB = accB[j][e];
                    sA = fmaf(x0.x, a0.x, sA); sA = fmaf(x0.y, a0.y, sA);
                    sA = fmaf(x0.z, a0.z, sA); sA = fmaf(x0.w, a0.w, sA);
                    sA = fmaf(x1.x, a1.x, sA); sA = fmaf(x1.y, a1.y, sA);
                    sA = fmaf(x1.z, a1.z, sA); sA = fmaf(x1.w, a1.w, sA);
                    sB = fmaf(x0.x, b0.x, sB); sB = fmaf(x0.y, b0.y, sB);
                    sB = fmaf(x0.z, b0.z, sB); sB = fmaf(x0.w, b0.w, sB);
                    sB = fmaf(x1.x, b1.x, sB); sB = fmaf(x1.y, b1.y, sB);
                    sB = fmaf(x1.z, b1.z, sB); sB = fmaf(x1.w, b1.w, sB);
                    accA[j][e] = sA; accB[j][e] = sB;
                }
            }
        }
    }

    // ---- butterfly over the 8 k-segs (masks 1,2,4 stay within seg-group) ----
    #pragma unroll
    for (int j = 0; j < 4; ++j)
        #pragma unroll
        for (int e = 0; e < 4; ++e) {
            float a = accA[j][e], b = accB[j][e];
            a += __shfl_xor(a, 1); a += __shfl_xor(a, 2); a += __shfl_xor(a, 4);
            b += __shfl_xor(b, 1); b += __shfl_xor(b, 2); b += __shfl_xor(b, 4);
            accA[j][e] = a; accB[j][e] = b;
        }

    __syncthreads();                  // all W reads done
    float* const slab = lds + 32 * KH;   // [64 rows][stride 33]

    if (seg == 0) {                   // each wave owns complete (row, e-quartet) outs
        #pragma unroll
        for (int j = 0; j < 4; ++j) {
            float* dst = slab + (rh * 32 + rgrp * 4 + j) * 33 + eq * 4;
            #pragma unroll
            for (int e = 0; e < 4; ++e) { dst[e] = accA[j][e]; dst[16 + e] = accB[j][e]; }
        }
    }
    __syncthreads();

    // ---- per-row epilogue: softplus noise, top-2, sparse softmax ----
    if (tid < ROWS_PER_BLK) {
        const int r = tid;
        const float* rowp = slab + r * 33;
        const size_t grow = (size_t)blockIdx.x * ROWS_PER_BLK + r;
        const float* nzp = noise + grow * NE;

        float m1 = -1e30f, m2 = -1e30f;
        int i1 = 0, i2 = 0;
        #pragma unroll
        for (int j = 0; j < NE; ++j) {
            const float z  = rowp[16 + j] + bns[j];
            const float sp = fmaxf(z, 0.f) + log1pf(expf(-fabsf(z)));  // jax softplus
            const float v  = fmaf(nzp[j], sp, rowp[j] + bfc[j]);
            if (v > m1)      { m2 = m1; i2 = i1; m1 = v; i1 = j; }     // ties -> lower idx
            else if (v > m2) { m2 = v;  i2 = j; }
        }
        const float e2  = expf(m2 - m1);
        const float inv = 1.f / (1.f + e2);

        float* po = out + grow * NE;
        #pragma unroll
        for (int j = 0; j < NE; ++j) {
            po[j] = (j == i1) ? inv : ((j == i2) ? e2 * inv : 0.f);
        }
        float* pi = out + (size_t)NROWS * NE + grow * 2;
        pi[0] = (float)i1;
        pi[1] = (float)i2;
    }
}

extern "C" void kernel_launch(void* const* d_in, const int* in_sizes, int n_in,
                              void* d_out, int out_size, void* d_ws, size_t ws_size,
                              hipStream_t stream)
{
    const float* x     = (const float*)d_in[0];
    const float* noise = (const float*)d_in[1];
    const float* Wfc   = (const float*)d_in[2];
    const float* bfc   = (const float*)d_in[3];
    const float* Wns   = (const float*)d_in[4];
    const float* bns   = (const float*)d_in[5];
    float* out = (float*)d_out;

    noisy_router_kernel<<<NROWS / ROWS_PER_BLK, 512, 0, stream>>>(
        x, noise, Wfc, bfc, Wns, bns, out);
}